// Round 1
// baseline (337.795 us; speedup 1.0000x reference)
//
#include <hip/hip_runtime.h>

#define C 32
#define NT 256

typedef float f32x4 __attribute__((ext_vector_type(4)));

__device__ __forceinline__ unsigned int f2bf(float f) {
    unsigned int u = __float_as_uint(f);
    return (u + 0x7FFFu + ((u >> 16) & 1u)) >> 16;   // RNE to bf16
}
__device__ __forceinline__ float bflo(unsigned int u) { return __uint_as_float(u << 16); }
__device__ __forceinline__ float bfhi(unsigned int u) { return __uint_as_float(u & 0xFFFF0000u); }

// K1: degree histogram via global atomics (400KB L2-resident, ~16 hits/addr)
// fused with x -> bf16 conversion (bandwidth work overlaps atomic latency).
__global__ __launch_bounds__(256) void k_deg_cvt(const int* __restrict__ dst,
                                                 int* __restrict__ ideg,
                                                 const float* __restrict__ x,
                                                 uint2* __restrict__ xb2,
                                                 int N, int E) {
    int gid = blockIdx.x * 256 + threadIdx.x;
    int gsz = gridDim.x * 256;
    for (int e = gid; e < E; e += gsz)
        atomicAdd(&ideg[dst[e]], 1);
    int total = N * 8;
    for (int i = gid; i < total; i += gsz) {
        f32x4 v = *(const f32x4*)(x + (size_t)i * 4);
        uint2 r;
        r.x = f2bf(v.x) | (f2bf(v.y) << 16);
        r.y = f2bf(v.z) | (f2bf(v.w) << 16);
        xb2[i] = r;
    }
}

// K2: exclusive scan of ideg -> rpos (CSR row starts). Single kernel:
// per-block Hillis-Steele scan + atomic-ticket block base (block ordering
// nondeterministic -> segments permuted at 1024-node granularity; disjoint
// and contiguous per node, which is all the gathers need).
__global__ __launch_bounds__(1024) void k_scan(const int* __restrict__ ideg,
                                               int* __restrict__ rpos,
                                               int* __restrict__ gcur, int N) {
    __shared__ int s[1024];
    __shared__ int base;
    int tid = threadIdx.x;
    int n = blockIdx.x * 1024 + tid;
    int v = (n < N) ? ideg[n] : 0;
    s[tid] = v;
    __syncthreads();
    for (int off = 1; off < 1024; off <<= 1) {
        int u = (tid >= off) ? s[tid - off] : 0;
        __syncthreads();
        s[tid] += u;
        __syncthreads();
    }
    if (tid == 1023) base = atomicAdd(gcur, s[1023]);
    __syncthreads();
    if (n < N) rpos[n] = base + s[tid] - v;   // exclusive start
}

// K3: scatter src into per-node segments. atomicAdd on rpos itself serves as
// the cursor; after this kernel rpos[n] == segment end (start + deg).
__global__ __launch_bounds__(256) void k_scatter(const int* __restrict__ src,
                                                 const int* __restrict__ dst,
                                                 int* __restrict__ rpos,
                                                 int* __restrict__ pk, int E) {
    int gid = blockIdx.x * 256 + threadIdx.x;
    int gsz = gridDim.x * 256;
    for (int e = gid; e < E; e += gsz) {
        int pos = atomicAdd(&rpos[dst[e]], 1);
        pk[pos] = src[e];
    }
}

// accumulate bf16 rows over pk[lo..hi) for lane-quarter lq (4 channels).
// 8 consecutive threads share a node -> each uint2 gather is one fully-used
// 64B line per 8-lane group.
__device__ __forceinline__ void accum_seg(const uint2* __restrict__ arr,
                                          const int* __restrict__ pk,
                                          int lo, int hi, int lq,
                                          float& a0, float& a1, float& a2, float& a3) {
#define ACC4(ux, uy) { a0 += bflo(ux); a1 += bfhi(ux); a2 += bflo(uy); a3 += bfhi(uy); }
    int j = lo;
    for (; j + 7 < hi; j += 8) {
        int s0 = __builtin_nontemporal_load(&pk[j]);
        int s1 = __builtin_nontemporal_load(&pk[j + 1]);
        int s2 = __builtin_nontemporal_load(&pk[j + 2]);
        int s3 = __builtin_nontemporal_load(&pk[j + 3]);
        int s4 = __builtin_nontemporal_load(&pk[j + 4]);
        int s5 = __builtin_nontemporal_load(&pk[j + 5]);
        int s6 = __builtin_nontemporal_load(&pk[j + 6]);
        int s7 = __builtin_nontemporal_load(&pk[j + 7]);
        uint2 u0 = arr[(size_t)s0 * 8 + lq];
        uint2 u1 = arr[(size_t)s1 * 8 + lq];
        uint2 u2 = arr[(size_t)s2 * 8 + lq];
        uint2 u3 = arr[(size_t)s3 * 8 + lq];
        uint2 u4 = arr[(size_t)s4 * 8 + lq];
        uint2 u5 = arr[(size_t)s5 * 8 + lq];
        uint2 u6 = arr[(size_t)s6 * 8 + lq];
        uint2 u7 = arr[(size_t)s7 * 8 + lq];
        ACC4(u0.x, u0.y) ACC4(u1.x, u1.y) ACC4(u2.x, u2.y) ACC4(u3.x, u3.y)
        ACC4(u4.x, u4.y) ACC4(u5.x, u5.y) ACC4(u6.x, u6.y) ACC4(u7.x, u7.y)
    }
    for (; j + 1 < hi; j += 2) {
        int s0 = __builtin_nontemporal_load(&pk[j]);
        int s1 = __builtin_nontemporal_load(&pk[j + 1]);
        uint2 u0 = arr[(size_t)s0 * 8 + lq];
        uint2 u1 = arr[(size_t)s1 * 8 + lq];
        ACC4(u0.x, u0.y) ACC4(u1.x, u1.y)
    }
    if (j < hi) {
        uint2 u0 = arr[(size_t)__builtin_nontemporal_load(&pk[j]) * 8 + lq];
        ACC4(u0.x, u0.y)
    }
#undef ACC4
}

// K4: t1 = deg*x - A@x (bf16 in/out, fp32 accum). Balanced 3125-block gather.
__global__ __launch_bounds__(NT) void k_mv1(const uint2* __restrict__ xb2,
                                            const int* __restrict__ pk,
                                            const int* __restrict__ rpos,
                                            const int* __restrict__ ideg,
                                            uint2* __restrict__ t1b2, int N) {
    int g = blockIdx.x * NT + threadIdx.x;
    int n = g >> 3;
    if (n >= N) return;
    int lq = g & 7;
    int dg = ideg[n];
    int hi = rpos[n];          // segment end after scatter
    int lo = hi - dg;
    float a0 = 0.f, a1 = 0.f, a2 = 0.f, a3 = 0.f;
    accum_seg(xb2, pk, lo, hi, lq, a0, a1, a2, a3);
    uint2 xs = xb2[(size_t)n * 8 + lq];
    float fdg = (float)dg;
    float t0 = fdg * bflo(xs.x) - a0;
    float t1v = fdg * bfhi(xs.x) - a1;
    float t2 = fdg * bflo(xs.y) - a2;
    float t3 = fdg * bfhi(xs.y) - a3;
    uint2 rr;
    rr.x = f2bf(t0) | (f2bf(t1v) << 16);
    rr.y = f2bf(t2) | (f2bf(t3) << 16);
    t1b2[(size_t)n * 8 + lq] = rr;   // regular store: keep t1b2 cache-resident for K5
}

// K5: y = w0*x + w1*t1 + w2*(deg*t1 - A@t1)
__global__ __launch_bounds__(NT) void k_mv2(const uint2* __restrict__ xb2,
                                            const uint2* __restrict__ t1b2,
                                            const int* __restrict__ pk,
                                            const int* __restrict__ rpos,
                                            const int* __restrict__ ideg,
                                            const float* __restrict__ wts,
                                            float* __restrict__ y, int N) {
    int g = blockIdx.x * NT + threadIdx.x;
    int n = g >> 3;
    if (n >= N) return;
    int lq = g & 7;
    int dg = ideg[n];
    int hi = rpos[n];
    int lo = hi - dg;
    float a0 = 0.f, a1 = 0.f, a2 = 0.f, a3 = 0.f;
    accum_seg(t1b2, pk, lo, hi, lq, a0, a1, a2, a3);
    uint2 xs = xb2[(size_t)n * 8 + lq];
    uint2 ts = t1b2[(size_t)n * 8 + lq];
    float w0 = wts[0], w1 = wts[1], w2 = wts[2];
    float fdg = (float)dg;
    float tv0 = bflo(ts.x), tv1 = bfhi(ts.x), tv2 = bflo(ts.y), tv3 = bfhi(ts.y);
    f32x4 r;
    r.x = w0 * bflo(xs.x) + w1 * tv0 + w2 * (fdg * tv0 - a0);
    r.y = w0 * bfhi(xs.x) + w1 * tv1 + w2 * (fdg * tv1 - a1);
    r.z = w0 * bflo(xs.y) + w1 * tv2 + w2 * (fdg * tv2 - a2);
    r.w = w0 * bfhi(xs.y) + w1 * tv3 + w2 * (fdg * tv3 - a3);
    size_t o = (size_t)n * C + lq * 4;
    __builtin_nontemporal_store(r, (f32x4*)(y + o));
}

extern "C" void kernel_launch(void* const* d_in, const int* in_sizes, int n_in,
                              void* d_out, int out_size, void* d_ws, size_t ws_size,
                              hipStream_t stream) {
    const float* x    = (const float*)d_in[0];
    const float* wts  = (const float*)d_in[1];
    const int*   esrc = (const int*)d_in[2];
    const int*   edst = (const int*)d_in[3];
    float*       y    = (float*)d_out;

    const int N = in_sizes[0] / C;                 // 100000
    const int E = in_sizes[2];                     // 1600000
    const int nc = N * C;

    char* p = (char*)d_ws;
    auto align16 = [](size_t s) { return (s + 15) & ~(size_t)15; };
    int* ideg  = (int*)p; p += align16((size_t)N * 4);
    int* gcur  = (int*)p; p += 16;
    int* rpos  = (int*)p; p += align16((size_t)N * 4);
    int* pk    = (int*)p; p += align16((size_t)E * 4);
    uint2* xb2 = (uint2*)p; p += align16((size_t)nc * 2);
    uint2* t1b2 = (uint2*)p; p += align16((size_t)nc * 2);
    (void)ws_size;

    // zero ideg + gcur (contiguous)
    hipMemsetAsync(ideg, 0, align16((size_t)N * 4) + 16, stream);

    const int EB = 2048;                           // 8 blocks/CU, 32 waves/CU
    const int nsb = (N + 1023) >> 10;              // 98 scan blocks
    const int gblocks = ((size_t)N * 8 + NT - 1) / NT;  // 3125

    k_deg_cvt<<<EB, 256, 0, stream>>>(edst, ideg, x, xb2, N, E);
    k_scan<<<nsb, 1024, 0, stream>>>(ideg, rpos, gcur, N);
    k_scatter<<<EB, 256, 0, stream>>>(esrc, edst, rpos, pk, E);
    k_mv1<<<gblocks, NT, 0, stream>>>(xb2, pk, rpos, ideg, t1b2, N);
    k_mv2<<<gblocks, NT, 0, stream>>>(xb2, t1b2, pk, rpos, ideg, wts, y, N);
}